// Round 5
// baseline (1297.821 us; speedup 1.0000x reference)
//
#include <hip/hip_runtime.h>
#include <cstddef>
#include <cstdint>

typedef __attribute__((ext_vector_type(8))) _Float16 half8;
typedef __attribute__((ext_vector_type(4))) float f32x4;
typedef _Float16 half_t;

#define NS 16
#define NN 32

// ---------------- workspace layout (bytes) ----------------
static const size_t OFF_H1P = 0;
static const size_t OFF_H2P = 138412032ull;
static const size_t OFF_ZR1 = OFF_H2P + 276824064ull;   // 415236096
static const size_t OFF_ZR2 = OFF_ZR1 + 67584ull;       // 415303680
static const size_t OFF_WT1 = OFF_ZR2 + 135168ull;      // 415438848
static const size_t OFF_WT2 = OFF_WT1 + 55296ull;       // 415494144
static const size_t OFF_WT3 = OFF_WT2 + 589824ull;      // 416083968
static const size_t OFF_SUMS = OFF_WT3 + 1179648ull;    // 417263616
static const size_t OFF_PRM = OFF_SUMS + 20480ull;      // 417284096
static const size_t OFF_TH  = OFF_PRM + 30720ull;       // 417314816

static __device__ __forceinline__ half8 sr8(half8 v, half8 t) {
    half8 r = v + t;
    half8 z = {};
#if defined(__has_builtin) && __has_builtin(__builtin_elementwise_max)
    return __builtin_elementwise_max(r, z);
#else
#pragma unroll
    for (int j = 0; j < 8; ++j) r[j] = r[j] > (_Float16)0 ? r[j] : (_Float16)0;
    return r;
#endif
}

// -------- conv1 weights: oc-contiguous f32 --------
__global__ __launch_bounds__(256) void transform1_k(
    const float* __restrict__ w1, float* __restrict__ wt1)
{
    int idx = blockIdx.x * 256 + threadIdx.x;
    if (idx >= 13824) return;
    int o = idx & 31, tap = (idx >> 5) % 9, ic = (idx / 288) % 3, s = idx / 864;
    wt1[idx] = w1[((s * 32 + o) * 3 + ic) * 9 + tap];
}

// -------- conv2/conv3 weights: ic-contiguous f16, BN scale of previous layer folded --------
__global__ __launch_bounds__(256) void wtrans2_k(
    const float* __restrict__ w2, const float* __restrict__ a1, half_t* __restrict__ wt2)
{
    int idx = blockIdx.x * 256 + threadIdx.x;
    if (idx >= 294912) return;
    int ic = idx & 31, oc = (idx >> 5) & 63, tap = (idx >> 11) % 9, s = idx / 18432;
    wt2[idx] = (half_t)(w2[((s * 64 + oc) * 32 + ic) * 9 + tap] * a1[s * 32 + ic]);
}

__global__ __launch_bounds__(256) void wtrans3_k(
    const float* __restrict__ w3, const float* __restrict__ a2, half_t* __restrict__ wt3)
{
    int idx = blockIdx.x * 256 + threadIdx.x;
    if (idx >= 589824) return;
    int ic = idx & 63, oc = (idx >> 6) & 63, tap = (idx >> 12) % 9, s = idx / 36864;
    wt3[idx] = (half_t)(w3[((s * 64 + oc) * 64 + ic) * 9 + tap] * a2[s * 64 + ic]);
}

// -------- conv1: 3->32 per seed, fp32 vector math, writes x-padded h1p (pre-BN) + stats --------
__global__ __launch_bounds__(256) void conv1_k(
    const float* __restrict__ x, const float* __restrict__ wt1,
    const float* __restrict__ b1, half_t* __restrict__ h1p,
    float* __restrict__ sums1)
{
    __shared__ float smem[8512];
    float* xt = smem;
    float* bounce = smem;
    float* statsl = smem + 8448;
    const int tile = blockIdx.x, s = blockIdx.y, n = blockIdx.z;
    const int tx = tile & 3, ty = tile >> 2, tid = threadIdx.x;

    for (int i = tid; i < 972; i += 256) {
        int ic = i / 324, rem = i - ic * 324;
        int py = rem / 18, px = rem - py * 18;
        int gy = ty * 16 + py - 1, gx = tx * 16 + px - 1;
        float v = 0.f;
        if ((unsigned)gy < 64u && (unsigned)gx < 64u)
            v = x[(size_t)(((s * NN + n) * 3 + ic) * 64 + gy) * 64 + gx];
        xt[i] = v;
    }
    if (tid < 64) statsl[tid] = 0.f;
    __syncthreads();

    const int px = tid & 15, py = tid >> 4;
    float acc[32];
#pragma unroll
    for (int o = 0; o < 32; ++o) acc[o] = 0.f;
#pragma unroll
    for (int ic = 0; ic < 3; ++ic)
#pragma unroll
        for (int ky = 0; ky < 3; ++ky)
#pragma unroll
            for (int kx = 0; kx < 3; ++kx) {
                float v = xt[ic * 324 + (py + ky) * 18 + px + kx];
                const float* wp = wt1 + ((s * 3 + ic) * 9 + ky * 3 + kx) * 32;
#pragma unroll
                for (int o = 0; o < 32; ++o) acc[o] = fmaf(wp[o], v, acc[o]);
            }
    const float* bp = b1 + s * 32;
#pragma unroll
    for (int o = 0; o < 32; ++o) acc[o] += bp[o];

    const int gy1 = ty * 16 + py, gxp = tx * 16 + px + 1;
    half8* dst = (half8*)(h1p + (size_t)(n * NS + s) * 135168 + (size_t)(gy1 * 66 + gxp) * 32);
#pragma unroll
    for (int k = 0; k < 4; ++k) {
        half8 v8;
#pragma unroll
        for (int j = 0; j < 8; ++j) v8[j] = (half_t)acc[k * 8 + j];
        dst[k] = v8;
    }
    __syncthreads();
#pragma unroll
    for (int o = 0; o < 32; ++o) bounce[tid * 33 + o] = acc[o];
    __syncthreads();
    {
        const int oc = tid & 31, grp = tid >> 5;
        float s1 = 0.f, s2 = 0.f;
#pragma unroll 4
        for (int j = 0; j < 32; ++j) {
            float v = bounce[(grp * 32 + j) * 33 + oc];
            s1 += v; s2 += v * v;
        }
        atomicAdd(&statsl[oc * 2], s1);
        atomicAdd(&statsl[oc * 2 + 1], s2);
    }
    __syncthreads();
    if (tid < 64)
        atomicAdd(&sums1[(s * 32 + (tid >> 1)) * 2 + (tid & 1)], statsl[tid]);
}

// -------- sums -> scale a, shift b, pre-act shift t = b/a (and f16 copy) --------
__global__ void bnparam_k(const float* __restrict__ sums, const float* __restrict__ g,
                          const float* __restrict__ be, float* __restrict__ a,
                          float* __restrict__ b, float* __restrict__ t,
                          half_t* __restrict__ th, int C)
{
    int ch = blockIdx.x * 256 + threadIdx.x;
    if (ch >= C) return;
    const float inv = 1.f / 131072.f;     // N*H*W = 32*64*64
    float mean = sums[ch * 2] * inv;
    float var = sums[ch * 2 + 1] * inv - mean * mean;
    float sc = g[ch] * rsqrtf(var + 1e-5f);
    a[ch] = sc;
    float bb = be[ch] - mean * sc;
    b[ch] = bb;
    float tt = bb / sc;
    t[ch] = tt;
    th[ch] = (half_t)tt;
}

// -------- fill pad columns + pad row with q = -(t+1), so relu(q + t) == 0 --------
__global__ __launch_bounds__(256) void padfill_k(
    half_t* __restrict__ img, half_t* __restrict__ zrow, const float* __restrict__ t,
    int C, int c8shift, long imgstride, int rowstride, long tot_cols, long tot)
{
    long idx = (long)blockIdx.x * 256 + threadIdx.x;
    if (idx >= tot) return;
    const int nc8m = (1 << c8shift) - 1;
    if (idx < tot_cols) {
        int c8 = (int)idx & nc8m; long r = idx >> c8shift;
        int side = (int)r & 1; r >>= 1;
        int y = (int)r & 63; r >>= 6;
        int si = (int)(r & 15); int ni = (int)(r >> 4);
        half8 q;
#pragma unroll
        for (int j = 0; j < 8; ++j) q[j] = (half_t)(-(t[si * C + c8 * 8 + j] + 1.0f));
        *(half8*)(img + (long)(ni * NS + si) * imgstride + (long)y * rowstride +
                  (side ? 65 : 0) * C + c8 * 8) = q;
    } else {
        long r2 = idx - tot_cols;
        int c8 = (int)r2 & nc8m; r2 >>= c8shift;
        int xx = (int)(r2 % 66); int si = (int)(r2 / 66);
        half8 q;
#pragma unroll
        for (int j = 0; j < 8; ++j) q[j] = (half_t)(-(t[si * C + c8 * 8 + j] + 1.0f));
        *(half8*)(zrow + ((long)(si * 66 + xx)) * C + c8 * 8) = q;
    }
}

// ======== conv2 ring: one block per (n,s) image, 8-row LDS ring, T14 staging ========
// ring row = 66 px * 80 B = 5280 B (80B px stride -> 2-way banks); obuf 36864; statsl
__device__ __forceinline__ void loadB2(half8 bf[2], const half_t* wb, int tap,
                                       int och, int l15, int g) {
#pragma unroll
    for (int nt = 0; nt < 2; ++nt)
        bf[nt] = *(const half8*)(wb + (tap * 64 + och * 32 + nt * 16 + l15) * 32 + g * 8);
}

__device__ __forceinline__ void comp2r(f32x4 acc[4][2], const half8 bf[2], const char* smem,
                                       int row, int kx, int l15, int g) {
    const char* rowp = smem + (row & 7) * 5280;
#pragma unroll
    for (int mt = 0; mt < 4; ++mt) {
        int p = mt * 16 + l15 + kx;
        half8 av = *(const half8*)(rowp + p * 80 + g * 16);
#pragma unroll
        for (int nt = 0; nt < 2; ++nt)
            acc[mt][nt] = __builtin_amdgcn_mfma_f32_16x16x32_f16(av, bf[nt], acc[mt][nt], 0, 0, 0);
    }
}

__global__ __launch_bounds__(512, 4) void conv2_k(
    const half_t* __restrict__ h1p, const half_t* __restrict__ zr1,
    const half_t* __restrict__ wt2, const float* __restrict__ b2,
    const half_t* __restrict__ th1, half_t* __restrict__ h2p,
    float* __restrict__ sums2)
{
    __shared__ __align__(16) char smem[79616]; // ring 42240 | obuf @42240 (36864) | statsl @79104
    half_t* obuf = (half_t*)(smem + 42240);
    float* statsl = (float*)(smem + 79104);
    const int n = blockIdx.x, s = blockIdx.y;
    const int tid = threadIdx.x;
    const int l = tid & 63, w = tid >> 6, l15 = l & 15, g = l >> 4;
    const int wy = w & 3, och = w >> 2;
    if (tid < 128) statsl[tid] = 0.f;

    const half_t* img = h1p + (size_t)(n * NS + s) * 135168;
    const half_t* zrow = zr1 + s * 2112;
    const half_t* wb = wt2 + (size_t)s * 18432;
    const int j = tid & 3;
    const half8 tshj = *(const half8*)(th1 + s * 32 + j * 8);

    // prologue: rows -1..4 -> slots 7,0..4
    for (int i = tid; i < 1584; i += 512) {
        int p = i >> 2;
        int rr = p / 66, col = p - rr * 66;
        int row = rr - 1;
        const half_t* rp = (row < 0) ? zrow : (img + (size_t)row * 2112);
        half8 v = sr8(*(const half8*)(rp + col * 32 + j * 8), tshj);
        *(half8*)(smem + (row & 7) * 5280 + col * 80 + j * 16) = v;
    }
    __syncthreads();

    float bias0 = b2[s * 64 + och * 32 + l15];
    float bias1 = b2[s * 64 + och * 32 + 16 + l15];
    float s1a0 = 0.f, s1a1 = 0.f, s2a0 = 0.f, s2a1 = 0.f;
    half_t* img2 = h2p + (size_t)(n * NS + s) * 270336;

    half8 bfa[2], bfb[2];
#pragma unroll 1
    for (int t = 0; t < 16; ++t) {
        // ---- issue stage loads for rows 4t+5..4t+8 (1056 chunks, <=3/thread) ----
        const int rowbase = 4 * t + 5;
        half8 st0, st1, st2;
        int sl0, sl1, sl2;
#define PREP2(K, ST, SL) { int idx = tid + K * 512; int p = idx >> 2; int rr = p / 66; \
        int col = p - rr * 66; int row = rowbase + rr; bool ok = (idx < 1056) && (row <= 64); \
        const half_t* rp = (row >= 64) ? zrow : (img + (size_t)row * 2112); \
        ST = *(const half8*)(rp + col * 32 + j * 8); \
        SL = ok ? ((row & 7) * 5280 + col * 80 + j * 16) : -1; }
        PREP2(0, st0, sl0)
        PREP2(1, st1, sl1)
        PREP2(2, st2, sl2)
#undef PREP2

        // ---- compute step t: output rows 4t..4t+3, wave owns row 4t+wy, oc half och ----
        f32x4 acc[4][2];
#pragma unroll
        for (int mt = 0; mt < 4; ++mt)
#pragma unroll
            for (int nt = 0; nt < 2; ++nt) acc[mt][nt] = (f32x4){0.f, 0.f, 0.f, 0.f};

        const int gy = 4 * t + wy;
        loadB2(bfa, wb, 0, och, l15, g);
#pragma unroll
        for (int tap = 0; tap < 9; ++tap) {
            int ky = tap / 3, kx = tap - ky * 3;
            if (tap & 1) {
                if (tap < 8) loadB2(bfa, wb, tap + 1, och, l15, g);
                comp2r(acc, bfb, smem, gy - 1 + ky, kx, l15, g);
            } else {
                if (tap < 8) loadB2(bfb, wb, tap + 1, och, l15, g);
                comp2r(acc, bfa, smem, gy - 1 + ky, kx, l15, g);
            }
        }

        // ---- bias + stats accumulate + obuf write (after barrier) ----
        __syncthreads();                    // ring reads + previous copy-out reads done
        if (sl0 >= 0) *(half8*)(smem + sl0) = sr8(st0, tshj);
        if (sl1 >= 0) *(half8*)(smem + sl1) = sr8(st1, tshj);
        if (sl2 >= 0) *(half8*)(smem + sl2) = sr8(st2, tshj);
#pragma unroll
        for (int mt = 0; mt < 4; ++mt)
#pragma unroll
            for (int nt = 0; nt < 2; ++nt) {
                f32x4 v = acc[mt][nt];
                float bias = nt ? bias1 : bias0;
#pragma unroll
                for (int r = 0; r < 4; ++r) {
                    float vv = v[r] + bias;
                    if (nt) { s1a1 += vv; s2a1 += vv * vv; } else { s1a0 += vv; s2a0 += vv * vv; }
                    obuf[(wy * 64 + mt * 16 + g * 4 + r) * 72 + och * 32 + nt * 16 + l15] = (half_t)vv;
                }
            }
        __syncthreads();                    // ring writes + obuf complete

        // ---- copy-out obuf -> h2p rows 4t..4t+3 cols 1..64 (coalesced) ----
        for (int i = tid; i < 2048; i += 512) {
            int c8 = i & 7, p = i >> 3;     // p = lr*64 + x
            int lr = p >> 6, xx = p & 63;
            *(half8*)(img2 + (size_t)(4 * t + lr) * 4224 + (xx + 1) * 64 + c8 * 8) =
                *(const half8*)(obuf + p * 72 + c8 * 8);
        }
    }

    // ---- stats flush ----
    s1a0 += __shfl_xor(s1a0, 16); s1a0 += __shfl_xor(s1a0, 32);
    s2a0 += __shfl_xor(s2a0, 16); s2a0 += __shfl_xor(s2a0, 32);
    s1a1 += __shfl_xor(s1a1, 16); s1a1 += __shfl_xor(s1a1, 32);
    s2a1 += __shfl_xor(s2a1, 16); s2a1 += __shfl_xor(s2a1, 32);
    if (l < 16) {
        atomicAdd(&statsl[(och * 32 + l15) * 2], s1a0);
        atomicAdd(&statsl[(och * 32 + l15) * 2 + 1], s2a0);
        atomicAdd(&statsl[(och * 32 + 16 + l15) * 2], s1a1);
        atomicAdd(&statsl[(och * 32 + 16 + l15) * 2 + 1], s2a1);
    }
    __syncthreads();
    if (tid < 128)
        atomicAdd(&sums2[(s * 64 + (tid >> 1)) * 2 + (tid & 1)], statsl[tid]);
}

// ======== conv3 ring: one block per (n,s) image, 8-row ring (128B px, XOR swizzle) ========
__device__ __forceinline__ void loadB3(half8 bf[2][2], const half_t* wb, int tap,
                                       int och, int l15, int g) {
#pragma unroll
    for (int nt = 0; nt < 2; ++nt) {
        const half_t* r = wb + (tap * 64 + och * 32 + nt * 16 + l15) * 64 + g * 8;
        bf[nt][0] = *(const half8*)(r);
        bf[nt][1] = *(const half8*)(r + 32);
    }
}

__device__ __forceinline__ void comp3r(f32x4 acc[4][2], const half8 bf[2][2], const char* smem,
                                       int row, int kx, int l15, int g) {
    const char* rowp = smem + (row & 7) * 8448;
#pragma unroll
    for (int mt = 0; mt < 4; ++mt) {
        int p = mt * 16 + l15 + kx;
        int base = p * 128, sw = (p & 7) << 4;
        half8 a0 = *(const half8*)(rowp + base + ((g * 16) ^ sw));
        half8 a1 = *(const half8*)(rowp + base + ((64 + g * 16) ^ sw));
#pragma unroll
        for (int nt = 0; nt < 2; ++nt) {
            acc[mt][nt] = __builtin_amdgcn_mfma_f32_16x16x32_f16(a0, bf[nt][0], acc[mt][nt], 0, 0, 0);
            acc[mt][nt] = __builtin_amdgcn_mfma_f32_16x16x32_f16(a1, bf[nt][1], acc[mt][nt], 0, 0, 0);
        }
    }
}

__global__ __launch_bounds__(512, 4) void conv3_k(
    const half_t* __restrict__ h2p, const half_t* __restrict__ zr2,
    const half_t* __restrict__ wt3, const float* __restrict__ b3,
    const half_t* __restrict__ th2, float* __restrict__ out,
    float* __restrict__ sums3)
{
    __shared__ __align__(16) char smem[68096]; // ring 8*8448=67584 | statsl @67584
    float* statsl = (float*)(smem + 67584);
    const int n = blockIdx.x, s = blockIdx.y;
    const int tid = threadIdx.x;
    const int l = tid & 63, w = tid >> 6, l15 = l & 15, g = l >> 4;
    const int wy = w & 3, och = w >> 2;
    if (tid < 128) statsl[tid] = 0.f;

    const half_t* img = h2p + (size_t)(n * NS + s) * 270336;
    const half_t* zrow = zr2 + s * 4224;
    const half_t* wb = wt3 + (size_t)s * 36864;
    const int j = tid & 7;
    const half8 tshj = *(const half8*)(th2 + s * 64 + j * 8);

    // prologue: rows -1..4 -> slots 7,0..4
    for (int i = tid; i < 3168; i += 512) {
        int p = i >> 3;
        int rr = p / 66, col = p - rr * 66;
        int row = rr - 1;
        const half_t* rp = (row < 0) ? zrow : (img + (size_t)row * 4224);
        half8 v = sr8(*(const half8*)(rp + col * 64 + j * 8), tshj);
        *(half8*)(smem + (row & 7) * 8448 + col * 128 + ((j * 16) ^ ((col & 7) << 4))) = v;
    }
    __syncthreads();

    float bias0 = b3[s * 64 + och * 32 + l15];
    float bias1 = b3[s * 64 + och * 32 + 16 + l15];
    float s1a0 = 0.f, s1a1 = 0.f, s2a0 = 0.f, s2a1 = 0.f;
    const size_t obase = (size_t)((s * NN + n) * 64) * 4096;

    half8 bfa[2][2], bfb[2][2];
#pragma unroll 1
    for (int t = 0; t < 16; ++t) {
        // ---- issue stage loads for rows 4t+5..4t+8 (2112 chunks, <=5/thread) ----
        const int rowbase = 4 * t + 5;
        half8 st0, st1, st2, st3, st4;
        int sl0, sl1, sl2, sl3, sl4;
#define PREP3(K, ST, SL) { int idx = tid + K * 512; int p = idx >> 3; int rr = p / 66; \
        int col = p - rr * 66; int row = rowbase + rr; bool ok = (idx < 2112) && (row <= 64); \
        const half_t* rp = (row >= 64) ? zrow : (img + (size_t)row * 4224); \
        ST = *(const half8*)(rp + col * 64 + j * 8); \
        SL = ok ? ((row & 7) * 8448 + col * 128 + ((j * 16) ^ ((col & 7) << 4))) : -1; }
        PREP3(0, st0, sl0)
        PREP3(1, st1, sl1)
        PREP3(2, st2, sl2)
        PREP3(3, st3, sl3)
        PREP3(4, st4, sl4)
#undef PREP3

        // ---- compute step t ----
        f32x4 acc[4][2];
#pragma unroll
        for (int mt = 0; mt < 4; ++mt)
#pragma unroll
            for (int nt = 0; nt < 2; ++nt) acc[mt][nt] = (f32x4){0.f, 0.f, 0.f, 0.f};

        const int gy = 4 * t + wy;
        loadB3(bfa, wb, 0, och, l15, g);
#pragma unroll
        for (int tap = 0; tap < 9; ++tap) {
            int ky = tap / 3, kx = tap - ky * 3;
            if (tap & 1) {
                if (tap < 8) loadB3(bfa, wb, tap + 1, och, l15, g);
                comp3r(acc, bfb, smem, gy - 1 + ky, kx, l15, g);
            } else {
                if (tap < 8) loadB3(bfb, wb, tap + 1, och, l15, g);
                comp3r(acc, bfa, smem, gy - 1 + ky, kx, l15, g);
            }
        }

        // ---- bias + stats + coalesced fp32 store (pre-BN3) ----
#pragma unroll
        for (int nt = 0; nt < 2; ++nt) {
            int c = och * 32 + nt * 16 + l15;
            float bias = nt ? bias1 : bias0;
#pragma unroll
            for (int mt = 0; mt < 4; ++mt) {
                f32x4 v = acc[mt][nt];
#pragma unroll
                for (int r = 0; r < 4; ++r) {
                    float vv = v[r] + bias;
                    v[r] = vv;
                    if (nt) { s1a1 += vv; s2a1 += vv * vv; } else { s1a0 += vv; s2a0 += vv * vv; }
                }
                *(f32x4*)(out + obase + (size_t)c * 4096 + gy * 64 + mt * 16 + g * 4) = v;
            }
        }

        // ---- ring update ----
        __syncthreads();                    // all ring reads of step t done
        if (sl0 >= 0) *(half8*)(smem + sl0) = sr8(st0, tshj);
        if (sl1 >= 0) *(half8*)(smem + sl1) = sr8(st1, tshj);
        if (sl2 >= 0) *(half8*)(smem + sl2) = sr8(st2, tshj);
        if (sl3 >= 0) *(half8*)(smem + sl3) = sr8(st3, tshj);
        if (sl4 >= 0) *(half8*)(smem + sl4) = sr8(st4, tshj);
        __syncthreads();                    // new rows visible for step t+1
    }

    // ---- stats flush ----
    s1a0 += __shfl_xor(s1a0, 16); s1a0 += __shfl_xor(s1a0, 32);
    s2a0 += __shfl_xor(s2a0, 16); s2a0 += __shfl_xor(s2a0, 32);
    s1a1 += __shfl_xor(s1a1, 16); s1a1 += __shfl_xor(s1a1, 32);
    s2a1 += __shfl_xor(s2a1, 16); s2a1 += __shfl_xor(s2a1, 32);
    if (l < 16) {
        atomicAdd(&statsl[(och * 32 + l15) * 2], s1a0);
        atomicAdd(&statsl[(och * 32 + l15) * 2 + 1], s2a0);
        atomicAdd(&statsl[(och * 32 + 16 + l15) * 2], s1a1);
        atomicAdd(&statsl[(och * 32 + 16 + l15) * 2 + 1], s2a1);
    }
    __syncthreads();
    if (tid < 128)
        atomicAdd(&sums3[(s * 64 + (tid >> 1)) * 2 + (tid & 1)], statsl[tid]);
}

// -------- final: in-place BN3+ReLU on d_out (grid-stride) --------
__global__ __launch_bounds__(256) void final_k(float* __restrict__ out,
                                               const float* __restrict__ a3,
                                               const float* __restrict__ b3p)
{
    const size_t stride = (size_t)gridDim.x * 256;
    for (size_t i = (size_t)blockIdx.x * 256 + threadIdx.x; i < 33554432ull; i += stride) {
        size_t e = i * 4;
        int ch = (int)((e >> 12) & 63) + (int)(e >> 23) * 64; // c + s*64
        float sc = a3[ch], sh = b3p[ch];
        f32x4 v = *(f32x4*)(out + e);
#pragma unroll
        for (int r = 0; r < 4; ++r) v[r] = fmaxf(fmaf(sc, v[r], sh), 0.f);
        *(f32x4*)(out + e) = v;
    }
}

extern "C" void kernel_launch(void* const* d_in, const int* in_sizes, int n_in,
                              void* d_out, int out_size, void* d_ws, size_t ws_size,
                              hipStream_t stream)
{
    const float* x   = (const float*)d_in[0];
    const float* w1  = (const float*)d_in[1];
    const float* b1  = (const float*)d_in[2];
    const float* g1  = (const float*)d_in[3];
    const float* be1 = (const float*)d_in[4];
    const float* w2  = (const float*)d_in[5];
    const float* b2  = (const float*)d_in[6];
    const float* g2  = (const float*)d_in[7];
    const float* be2 = (const float*)d_in[8];
    const float* w3  = (const float*)d_in[9];
    const float* b3  = (const float*)d_in[10];
    const float* g3  = (const float*)d_in[11];
    const float* be3 = (const float*)d_in[12];

    char* ws = (char*)d_ws;
    half_t* h1p = (half_t*)(ws + OFF_H1P);
    half_t* h2p = (half_t*)(ws + OFF_H2P);
    half_t* zr1 = (half_t*)(ws + OFF_ZR1);
    half_t* zr2 = (half_t*)(ws + OFF_ZR2);
    float*  wt1 = (float*)(ws + OFF_WT1);
    half_t* wt2 = (half_t*)(ws + OFF_WT2);
    half_t* wt3 = (half_t*)(ws + OFF_WT3);
    float*  sums = (float*)(ws + OFF_SUMS);
    float *s1v = sums, *s2v = sums + 1024, *s3v = sums + 3072;
    float*  prm = (float*)(ws + OFF_PRM);
    float *a1 = prm,        *b1p = prm + 512,  *t1 = prm + 1024;
    float *a2 = prm + 1536, *b2p = prm + 2560, *t2 = prm + 3584;
    float *a3 = prm + 4608, *b3p = prm + 5632, *t3 = prm + 6656;
    half_t* th = (half_t*)(ws + OFF_TH);
    half_t *th1 = th, *th2 = th + 512, *th3 = th + 1536;
    float* out = (float*)d_out;

    hipMemsetAsync(ws + OFF_SUMS, 0, 20480, stream);
    transform1_k<<<54, 256, 0, stream>>>(w1, wt1);
    dim3 grid1(16, 16, 32); // (tile, seed, sample)
    conv1_k<<<grid1, 256, 0, stream>>>(x, wt1, b1, h1p, s1v);
    bnparam_k<<<2, 256, 0, stream>>>(s1v, g1, be1, a1, b1p, t1, th1, 512);
    padfill_k<<<1041, 256, 0, stream>>>(h1p, zr1, t1, 32, 2, 135168L, 2112, 262144L, 266368L);
    wtrans2_k<<<1152, 256, 0, stream>>>(w2, a1, wt2);
    dim3 gridr(32, 16); // (sample, seed)
    conv2_k<<<gridr, 512, 0, stream>>>(h1p, zr1, wt2, b2, th1, h2p, s2v);
    bnparam_k<<<4, 256, 0, stream>>>(s2v, g2, be2, a2, b2p, t2, th2, 1024);
    padfill_k<<<2081, 256, 0, stream>>>(h2p, zr2, t2, 64, 3, 270336L, 4224, 524288L, 532736L);
    wtrans3_k<<<2304, 256, 0, stream>>>(w3, a2, wt3);
    conv3_k<<<gridr, 512, 0, stream>>>(h2p, zr2, wt3, b3, th2, out, s3v);
    bnparam_k<<<4, 256, 0, stream>>>(s3v, g3, be3, a3, b3p, t3, th3, 1024);
    final_k<<<4096, 256, 0, stream>>>(out, a3, b3p);
}

// Round 6
// 903.581 us; speedup vs baseline: 1.4363x; 1.4363x over previous
//
#include <hip/hip_runtime.h>
#include <cstddef>
#include <cstdint>

typedef __attribute__((ext_vector_type(8))) _Float16 half8;
typedef __attribute__((ext_vector_type(4))) float f32x4;
typedef _Float16 half_t;

#define NS 16
#define NN 32

// ---------------- workspace layout (bytes) ----------------
static const size_t OFF_H1P = 0;
static const size_t OFF_H2P = 138412032ull;
static const size_t OFF_ZR1 = OFF_H2P + 276824064ull;   // 415236096
static const size_t OFF_ZR2 = OFF_ZR1 + 67584ull;       // 415303680
static const size_t OFF_WT1 = OFF_ZR2 + 135168ull;      // 415438848
static const size_t OFF_WT2 = OFF_WT1 + 55296ull;       // 415494144
static const size_t OFF_WT3 = OFF_WT2 + 589824ull;      // 416083968
static const size_t OFF_SUMS = OFF_WT3 + 1179648ull;    // 417263616
static const size_t OFF_PRM = OFF_SUMS + 20480ull;      // 417284096
static const size_t OFF_TH  = OFF_PRM + 30720ull;       // 417314816

static __device__ __forceinline__ half8 sr8(half8 v, half8 t) {
    half8 r = v + t;
    half8 z = {};
#if defined(__has_builtin) && __has_builtin(__builtin_elementwise_max)
    return __builtin_elementwise_max(r, z);
#else
#pragma unroll
    for (int j = 0; j < 8; ++j) r[j] = r[j] > (_Float16)0 ? r[j] : (_Float16)0;
    return r;
#endif
}

// -------- conv1 weights: oc-contiguous f32 --------
__global__ __launch_bounds__(256) void transform1_k(
    const float* __restrict__ w1, float* __restrict__ wt1)
{
    int idx = blockIdx.x * 256 + threadIdx.x;
    if (idx >= 13824) return;
    int o = idx & 31, tap = (idx >> 5) % 9, ic = (idx / 288) % 3, s = idx / 864;
    wt1[idx] = w1[((s * 32 + o) * 3 + ic) * 9 + tap];
}

// -------- conv2/conv3 weights: ic-contiguous f16, BN scale of previous layer folded --------
__global__ __launch_bounds__(256) void wtrans2_k(
    const float* __restrict__ w2, const float* __restrict__ a1, half_t* __restrict__ wt2)
{
    int idx = blockIdx.x * 256 + threadIdx.x;
    if (idx >= 294912) return;
    int ic = idx & 31, oc = (idx >> 5) & 63, tap = (idx >> 11) % 9, s = idx / 18432;
    wt2[idx] = (half_t)(w2[((s * 64 + oc) * 32 + ic) * 9 + tap] * a1[s * 32 + ic]);
}

__global__ __launch_bounds__(256) void wtrans3_k(
    const float* __restrict__ w3, const float* __restrict__ a2, half_t* __restrict__ wt3)
{
    int idx = blockIdx.x * 256 + threadIdx.x;
    if (idx >= 589824) return;
    int ic = idx & 63, oc = (idx >> 6) & 63, tap = (idx >> 12) % 9, s = idx / 36864;
    wt3[idx] = (half_t)(w3[((s * 64 + oc) * 64 + ic) * 9 + tap] * a2[s * 64 + ic]);
}

// -------- conv1: 3->32 per seed, fp32 vector math, writes x-padded h1p (pre-BN) + stats --------
__global__ __launch_bounds__(256) void conv1_k(
    const float* __restrict__ x, const float* __restrict__ wt1,
    const float* __restrict__ b1, half_t* __restrict__ h1p,
    float* __restrict__ sums1)
{
    __shared__ float smem[8512];
    float* xt = smem;
    float* bounce = smem;
    float* statsl = smem + 8448;
    const int tile = blockIdx.x, s = blockIdx.y, n = blockIdx.z;
    const int tx = tile & 3, ty = tile >> 2, tid = threadIdx.x;

    for (int i = tid; i < 972; i += 256) {
        int ic = i / 324, rem = i - ic * 324;
        int py = rem / 18, px = rem - py * 18;
        int gy = ty * 16 + py - 1, gx = tx * 16 + px - 1;
        float v = 0.f;
        if ((unsigned)gy < 64u && (unsigned)gx < 64u)
            v = x[(size_t)(((s * NN + n) * 3 + ic) * 64 + gy) * 64 + gx];
        xt[i] = v;
    }
    if (tid < 64) statsl[tid] = 0.f;
    __syncthreads();

    const int px = tid & 15, py = tid >> 4;
    float acc[32];
#pragma unroll
    for (int o = 0; o < 32; ++o) acc[o] = 0.f;
#pragma unroll
    for (int ic = 0; ic < 3; ++ic)
#pragma unroll
        for (int ky = 0; ky < 3; ++ky)
#pragma unroll
            for (int kx = 0; kx < 3; ++kx) {
                float v = xt[ic * 324 + (py + ky) * 18 + px + kx];
                const float* wp = wt1 + ((s * 3 + ic) * 9 + ky * 3 + kx) * 32;
#pragma unroll
                for (int o = 0; o < 32; ++o) acc[o] = fmaf(wp[o], v, acc[o]);
            }
    const float* bp = b1 + s * 32;
#pragma unroll
    for (int o = 0; o < 32; ++o) acc[o] += bp[o];

    const int gy1 = ty * 16 + py, gxp = tx * 16 + px + 1;
    half8* dst = (half8*)(h1p + (size_t)(n * NS + s) * 135168 + (size_t)(gy1 * 66 + gxp) * 32);
#pragma unroll
    for (int k = 0; k < 4; ++k) {
        half8 v8;
#pragma unroll
        for (int j = 0; j < 8; ++j) v8[j] = (half_t)acc[k * 8 + j];
        dst[k] = v8;
    }
    __syncthreads();
#pragma unroll
    for (int o = 0; o < 32; ++o) bounce[tid * 33 + o] = acc[o];
    __syncthreads();
    {
        const int oc = tid & 31, grp = tid >> 5;
        float s1 = 0.f, s2 = 0.f;
#pragma unroll 4
        for (int jj = 0; jj < 32; ++jj) {
            float v = bounce[(grp * 32 + jj) * 33 + oc];
            s1 += v; s2 += v * v;
        }
        atomicAdd(&statsl[oc * 2], s1);
        atomicAdd(&statsl[oc * 2 + 1], s2);
    }
    __syncthreads();
    if (tid < 64)
        atomicAdd(&sums1[(s * 32 + (tid >> 1)) * 2 + (tid & 1)], statsl[tid]);
}

// -------- sums -> scale a, shift b, pre-act shift t = b/a (and f16 copy) --------
__global__ void bnparam_k(const float* __restrict__ sums, const float* __restrict__ g,
                          const float* __restrict__ be, float* __restrict__ a,
                          float* __restrict__ b, float* __restrict__ t,
                          half_t* __restrict__ th, int C)
{
    int ch = blockIdx.x * 256 + threadIdx.x;
    if (ch >= C) return;
    const float inv = 1.f / 131072.f;     // N*H*W = 32*64*64
    float mean = sums[ch * 2] * inv;
    float var = sums[ch * 2 + 1] * inv - mean * mean;
    float sc = g[ch] * rsqrtf(var + 1e-5f);
    a[ch] = sc;
    float bb = be[ch] - mean * sc;
    b[ch] = bb;
    float tt = bb / sc;
    t[ch] = tt;
    th[ch] = (half_t)tt;
}

// -------- fill pad columns + pad row with q = -(t+1), so relu(q + t) == 0 --------
__global__ __launch_bounds__(256) void padfill_k(
    half_t* __restrict__ img, half_t* __restrict__ zrow, const float* __restrict__ t,
    int C, int c8shift, long imgstride, int rowstride, long tot_cols, long tot)
{
    long idx = (long)blockIdx.x * 256 + threadIdx.x;
    if (idx >= tot) return;
    const int nc8m = (1 << c8shift) - 1;
    if (idx < tot_cols) {
        int c8 = (int)idx & nc8m; long r = idx >> c8shift;
        int side = (int)r & 1; r >>= 1;
        int y = (int)r & 63; r >>= 6;
        int si = (int)(r & 15); int ni = (int)(r >> 4);
        half8 q;
#pragma unroll
        for (int j = 0; j < 8; ++j) q[j] = (half_t)(-(t[si * C + c8 * 8 + j] + 1.0f));
        *(half8*)(img + (long)(ni * NS + si) * imgstride + (long)y * rowstride +
                  (side ? 65 : 0) * C + c8 * 8) = q;
    } else {
        long r2 = idx - tot_cols;
        int c8 = (int)r2 & nc8m; r2 >>= c8shift;
        int xx = (int)(r2 % 66); int si = (int)(r2 / 66);
        half8 q;
#pragma unroll
        for (int j = 0; j < 8; ++j) q[j] = (half_t)(-(t[si * C + c8 * 8 + j] + 1.0f));
        *(half8*)(zrow + ((long)(si * 66 + xx)) * C + c8 * 8) = q;
    }
}

// ======== conv2: 64x4 tile, 512 thr, phase-split stage (A rows -1..2 / B rows 3..4) ========
__device__ __forceinline__ void loadB2(half8 bf[2], const half_t* wb, int tap,
                                       int och, int l15, int g) {
#pragma unroll
    for (int nt = 0; nt < 2; ++nt)
        bf[nt] = *(const half8*)(wb + (tap * 64 + och * 32 + nt * 16 + l15) * 32 + g * 8);
}

__device__ __forceinline__ void comp2(f32x4 acc[4][2], const half8 bf[2], const char* rowp,
                                      int kx, int l15, int g) {
#pragma unroll
    for (int mt = 0; mt < 4; ++mt) {
        int px = mt * 16 + l15 + kx;
        half8 av = *(const half8*)(rowp + px * 80 + g * 16);
#pragma unroll
        for (int nt = 0; nt < 2; ++nt)
            acc[mt][nt] = __builtin_amdgcn_mfma_f32_16x16x32_f16(av, bf[nt], acc[mt][nt], 0, 0, 0);
    }
}

__global__ __launch_bounds__(512, 4) void conv2_k(
    const half_t* __restrict__ h1p, const half_t* __restrict__ zr1,
    const half_t* __restrict__ wt2, const float* __restrict__ b2,
    const half_t* __restrict__ th1, half_t* __restrict__ h2p,
    float* __restrict__ sums2)
{
    __shared__ __align__(16) char smem[37376]; // A-tile 6*5280=31680 / obuf 36864 union; statsl @36864
    half_t* obuf = (half_t*)smem;
    float* statsl = (float*)(smem + 36864);
    const int ty = blockIdx.x, s = blockIdx.y, n = blockIdx.z;
    const int tid = threadIdx.x;
    const int l = tid & 63, w = tid >> 6, l15 = l & 15, g = l >> 4;
    const int wy = w & 3, och = w >> 2;
    const int ty4 = ty * 4;
    if (tid < 128) statsl[tid] = 0.f;

    const half_t* img = h1p + (size_t)(n * NS + s) * 135168;
    const half_t* zrow = zr1 + s * 2112;
    const half_t* wb = wt2 + (size_t)s * 18432;
    const int j = tid & 3;
    const half8 tshj = *(const half8*)(th1 + s * 32 + j * 8);

    // ---- A-stage issue: rows ty4-1..ty4+2 -> slots 0..3 (1056 chunks, 3 PREPs) ----
    half8 sa0, sa1, sa2; int aa0, aa1, aa2;
#define PREPA(K, ST, SL) { int idx = tid + K * 512; int p = idx >> 2; int rr = p / 66; \
    int col = p - rr * 66; int row = ty4 - 1 + rr; bool ok = idx < 1056; \
    const half_t* rp = ((unsigned)row < 64u) ? (img + (size_t)row * 2112) : zrow; \
    ST = *(const half8*)(rp + col * 32 + j * 8); \
    SL = ok ? (rr * 5280 + col * 80 + j * 16) : -1; }
    PREPA(0, sa0, aa0)
    PREPA(1, sa1, aa1)
    PREPA(2, sa2, aa2)
#undef PREPA
    // ---- B-stage issue (held across compute-A): rows ty4+3, ty4+4 -> slots 4,5 ----
    half8 sb0, sb1; int ab0, ab1;
#define PREPB(K, ST, SL) { int idx = tid + K * 512; int p = idx >> 2; int rr = p / 66; \
    int col = p - rr * 66; int row = ty4 + 3 + rr; bool ok = idx < 528; \
    const half_t* rp = ((unsigned)row < 64u) ? (img + (size_t)row * 2112) : zrow; \
    ST = *(const half8*)(rp + col * 32 + j * 8); \
    SL = ok ? ((4 + rr) * 5280 + col * 80 + j * 16) : -1; }
    PREPB(0, sb0, ab0)
    PREPB(1, sb1, ab1)
#undef PREPB
    if (aa0 >= 0) *(half8*)(smem + aa0) = sr8(sa0, tshj);
    if (aa1 >= 0) *(half8*)(smem + aa1) = sr8(sa1, tshj);
    if (aa2 >= 0) *(half8*)(smem + aa2) = sr8(sa2, tshj);
    __syncthreads();

    f32x4 acc[4][2];
#pragma unroll
    for (int mt = 0; mt < 4; ++mt)
#pragma unroll
        for (int nt = 0; nt < 2; ++nt) acc[mt][nt] = (f32x4){0.f, 0.f, 0.f, 0.f};

    half8 bfa[2], bfb[2];
    loadB2(bfa, wb, 0, och, l15, g);
    // phase A: taps 0..2 (ky=0 -> slot wy)
    const char* rowpA = smem + wy * 5280;
#pragma unroll
    for (int tap = 0; tap < 3; ++tap) {
        if ((tap & 1) == 0) { loadB2(bfb, wb, tap + 1, och, l15, g); comp2(acc, bfa, rowpA, tap, l15, g); }
        else                { loadB2(bfa, wb, tap + 1, och, l15, g); comp2(acc, bfb, rowpA, tap, l15, g); }
    }
    // write B rows (slots 4,5 — not read by phase A, no barrier needed before)
    if (ab0 >= 0) *(half8*)(smem + ab0) = sr8(sb0, tshj);
    if (ab1 >= 0) *(half8*)(smem + ab1) = sr8(sb1, tshj);
    __syncthreads();
    // phase B: taps 3..8 (ky=1,2 -> slots wy+1, wy+2)
#pragma unroll
    for (int tap = 3; tap < 9; ++tap) {
        int ky = tap / 3, kx = tap - ky * 3;
        const char* rowp = smem + (wy + ky) * 5280;
        if ((tap & 1) == 1) { if (tap < 8) loadB2(bfa, wb, tap + 1, och, l15, g); comp2(acc, bfb, rowp, kx, l15, g); }
        else                { if (tap < 8) loadB2(bfb, wb, tap + 1, och, l15, g); comp2(acc, bfa, rowp, kx, l15, g); }
    }

    // ---- epilogue: bias + register stats + obuf bounce + coalesced f16 copy-out ----
    float bias0 = b2[s * 64 + och * 32 + l15];
    float bias1 = b2[s * 64 + och * 32 + 16 + l15];
    float s10 = 0.f, s20 = 0.f, s11 = 0.f, s21 = 0.f;
    __syncthreads();                      // A-tile reads done -> obuf may alias
#pragma unroll
    for (int mt = 0; mt < 4; ++mt)
#pragma unroll
        for (int nt = 0; nt < 2; ++nt) {
            float bias = nt ? bias1 : bias0;
#pragma unroll
            for (int r = 0; r < 4; ++r) {
                float vv = acc[mt][nt][r] + bias;
                if (nt) { s11 += vv; s21 += vv * vv; } else { s10 += vv; s20 += vv * vv; }
                obuf[(wy * 64 + mt * 16 + g * 4 + r) * 72 + och * 32 + nt * 16 + l15] = (half_t)vv;
            }
        }
    __syncthreads();

    half_t* img2 = h2p + (size_t)(n * NS + s) * 270336;
    for (int i = tid; i < 2048; i += 512) {
        int c8 = i & 7, p = i >> 3, lr = p >> 6, xx = p & 63;
        *(half8*)(img2 + (size_t)(ty4 + lr) * 4224 + (xx + 1) * 64 + c8 * 8) =
            *(const half8*)(obuf + p * 72 + c8 * 8);
    }
    s10 += __shfl_xor(s10, 16); s10 += __shfl_xor(s10, 32);
    s20 += __shfl_xor(s20, 16); s20 += __shfl_xor(s20, 32);
    s11 += __shfl_xor(s11, 16); s11 += __shfl_xor(s11, 32);
    s21 += __shfl_xor(s21, 16); s21 += __shfl_xor(s21, 32);
    if (l < 16) {
        atomicAdd(&statsl[(och * 32 + l15) * 2], s10);
        atomicAdd(&statsl[(och * 32 + l15) * 2 + 1], s20);
        atomicAdd(&statsl[(och * 32 + 16 + l15) * 2], s11);
        atomicAdd(&statsl[(och * 32 + 16 + l15) * 2 + 1], s21);
    }
    __syncthreads();
    if (tid < 128)
        atomicAdd(&sums2[(s * 64 + (tid >> 1)) * 2 + (tid & 1)], statsl[tid]);
}

// ======== conv3: 64x4 tile, 512 thr, phase-split stage + per-kc B dbuf chain ========
__device__ __forceinline__ void loadB3k(half8 bf[2], const half_t* wb, int tap, int kc,
                                        int och, int l15, int g) {
#pragma unroll
    for (int nt = 0; nt < 2; ++nt)
        bf[nt] = *(const half8*)(wb + (tap * 64 + och * 32 + nt * 16 + l15) * 64 + kc * 32 + g * 8);
}

__device__ __forceinline__ void comp3k(f32x4 acc[4][2], const half8 bf[2], const char* rowp,
                                       int kx, int kc, int l15, int g) {
#pragma unroll
    for (int mt = 0; mt < 4; ++mt) {
        int px = mt * 16 + l15 + kx;
        int base = px * 128, sw = (px & 7) << 4;
        half8 a = *(const half8*)(rowp + base + ((kc * 64 + g * 16) ^ sw));
#pragma unroll
        for (int nt = 0; nt < 2; ++nt)
            acc[mt][nt] = __builtin_amdgcn_mfma_f32_16x16x32_f16(a, bf[nt], acc[mt][nt], 0, 0, 0);
    }
}

__global__ __launch_bounds__(512, 4) void conv3_k(
    const half_t* __restrict__ h2p, const half_t* __restrict__ zr2,
    const half_t* __restrict__ wt3, const float* __restrict__ b3,
    const half_t* __restrict__ th2, float* __restrict__ out,
    float* __restrict__ sums3)
{
    __shared__ __align__(16) char smem[51200];  // 6 row-slots * 8448 = 50688 + statsl
    float* statsl = (float*)(smem + 50688);
    const int ty = blockIdx.x, s = blockIdx.y, n = blockIdx.z;
    const int tid = threadIdx.x;
    const int l = tid & 63, w = tid >> 6, l15 = l & 15, g = l >> 4;
    const int wy = w & 3, och = w >> 2;
    const int ty4 = ty * 4;
    if (tid < 128) statsl[tid] = 0.f;

    const half_t* img = h2p + (size_t)(n * NS + s) * 270336;
    const half_t* zrow = zr2 + s * 4224;
    const half_t* wb = wt3 + (size_t)s * 36864;
    const int j = tid & 7;
    const half8 tshj = *(const half8*)(th2 + s * 64 + j * 8);

    // ---- A-stage issue: rows ty4-1..ty4+2 -> slots 0..3 (2112 chunks, 5 PREPs) ----
    half8 sa0, sa1, sa2, sa3, sa4; int aa0, aa1, aa2, aa3, aa4;
#define PREPA(K, ST, SL) { int idx = tid + K * 512; int p = idx >> 3; int rr = p / 66; \
    int col = p - rr * 66; int row = ty4 - 1 + rr; bool ok = idx < 2112; \
    const half_t* rp = ((unsigned)row < 64u) ? (img + (size_t)row * 4224) : zrow; \
    ST = *(const half8*)(rp + col * 64 + j * 8); \
    SL = ok ? (rr * 8448 + col * 128 + ((j * 16) ^ ((col & 7) << 4))) : -1; }
    PREPA(0, sa0, aa0)
    PREPA(1, sa1, aa1)
    PREPA(2, sa2, aa2)
    PREPA(3, sa3, aa3)
    PREPA(4, sa4, aa4)
#undef PREPA
    // ---- B-stage issue (held across compute-A): rows ty4+3, ty4+4 -> slots 4,5 ----
    half8 sb0, sb1, sb2; int ab0, ab1, ab2;
#define PREPB(K, ST, SL) { int idx = tid + K * 512; int p = idx >> 3; int rr = p / 66; \
    int col = p - rr * 66; int row = ty4 + 3 + rr; bool ok = idx < 1056; \
    const half_t* rp = ((unsigned)row < 64u) ? (img + (size_t)row * 4224) : zrow; \
    ST = *(const half8*)(rp + col * 64 + j * 8); \
    SL = ok ? ((4 + rr) * 8448 + col * 128 + ((j * 16) ^ ((col & 7) << 4))) : -1; }
    PREPB(0, sb0, ab0)
    PREPB(1, sb1, ab1)
    PREPB(2, sb2, ab2)
#undef PREPB
    if (aa0 >= 0) *(half8*)(smem + aa0) = sr8(sa0, tshj);
    if (aa1 >= 0) *(half8*)(smem + aa1) = sr8(sa1, tshj);
    if (aa2 >= 0) *(half8*)(smem + aa2) = sr8(sa2, tshj);
    if (aa3 >= 0) *(half8*)(smem + aa3) = sr8(sa3, tshj);
    if (aa4 >= 0) *(half8*)(smem + aa4) = sr8(sa4, tshj);
    __syncthreads();

    f32x4 acc[4][2];
#pragma unroll
    for (int mt = 0; mt < 4; ++mt)
#pragma unroll
        for (int nt = 0; nt < 2; ++nt) acc[mt][nt] = (f32x4){0.f, 0.f, 0.f, 0.f};

    // 18-step (kc,tap) chain: A = taps 0..2 x kc0,kc1 ; B = taps 3..8 x kc0,kc1
    const int UT[19] = {0,1,2,0,1,2, 3,4,5,6,7,8, 3,4,5,6,7,8, 0};
    const int UK[19] = {0,0,0,1,1,1, 0,0,0,0,0,0, 1,1,1,1,1,1, 0};
    half8 bfa[2], bfb[2];
    loadB3k(bfa, wb, UT[0], UK[0], och, l15, g);
    const char* rowpA = smem + wy * 8448;
#pragma unroll
    for (int u = 0; u < 6; ++u) {
        if ((u & 1) == 0) { loadB3k(bfb, wb, UT[u+1], UK[u+1], och, l15, g); comp3k(acc, bfa, rowpA, UT[u], UK[u], l15, g); }
        else              { loadB3k(bfa, wb, UT[u+1], UK[u+1], och, l15, g); comp3k(acc, bfb, rowpA, UT[u], UK[u], l15, g); }
    }
    // write B rows (slots 4,5 — untouched by phase A)
    if (ab0 >= 0) *(half8*)(smem + ab0) = sr8(sb0, tshj);
    if (ab1 >= 0) *(half8*)(smem + ab1) = sr8(sb1, tshj);
    if (ab2 >= 0) *(half8*)(smem + ab2) = sr8(sb2, tshj);
    __syncthreads();
#pragma unroll
    for (int u = 6; u < 18; ++u) {
        int tap = UT[u];
        int ky = tap / 3, kx = tap - ky * 3;
        const char* rowp = smem + (wy + ky) * 8448;
        if ((u & 1) == 0) { if (u < 17) loadB3k(bfb, wb, UT[u+1], UK[u+1], och, l15, g); comp3k(acc, bfa, rowp, kx, UK[u], l15, g); }
        else              { if (u < 17) loadB3k(bfa, wb, UT[u+1], UK[u+1], och, l15, g); comp3k(acc, bfb, rowp, kx, UK[u], l15, g); }
    }

    // ---- epilogue: bias + register stats + coalesced fp32 store (pre-BN3) ----
    float bias0 = b3[s * 64 + och * 32 + l15];
    float bias1 = b3[s * 64 + och * 32 + 16 + l15];
    float s10 = 0.f, s20 = 0.f, s11 = 0.f, s21 = 0.f;
    const int gy = ty4 + wy;
    float* obase = out + (size_t)((s * NN + n) * 64) * 4096;
#pragma unroll
    for (int mt = 0; mt < 4; ++mt)
#pragma unroll
        for (int nt = 0; nt < 2; ++nt) {
            int c = och * 32 + nt * 16 + l15;
            f32x4 v = acc[mt][nt];
            float bias = nt ? bias1 : bias0;
#pragma unroll
            for (int r = 0; r < 4; ++r) {
                float vv = v[r] + bias;
                v[r] = vv;
                if (nt) { s11 += vv; s21 += vv * vv; } else { s10 += vv; s20 += vv * vv; }
            }
            *(f32x4*)(obase + (size_t)c * 4096 + gy * 64 + mt * 16 + g * 4) = v;
        }

    s10 += __shfl_xor(s10, 16); s10 += __shfl_xor(s10, 32);
    s20 += __shfl_xor(s20, 16); s20 += __shfl_xor(s20, 32);
    s11 += __shfl_xor(s11, 16); s11 += __shfl_xor(s11, 32);
    s21 += __shfl_xor(s21, 16); s21 += __shfl_xor(s21, 32);
    if (l < 16) {
        atomicAdd(&statsl[(och * 32 + l15) * 2], s10);
        atomicAdd(&statsl[(och * 32 + l15) * 2 + 1], s20);
        atomicAdd(&statsl[(och * 32 + 16 + l15) * 2], s11);
        atomicAdd(&statsl[(och * 32 + 16 + l15) * 2 + 1], s21);
    }
    __syncthreads();
    if (tid < 128)
        atomicAdd(&sums3[(s * 64 + (tid >> 1)) * 2 + (tid & 1)], statsl[tid]);
}

// -------- final: in-place BN3+ReLU on d_out (grid-stride) --------
__global__ __launch_bounds__(256) void final_k(float* __restrict__ out,
                                               const float* __restrict__ a3,
                                               const float* __restrict__ b3p)
{
    const size_t stride = (size_t)gridDim.x * 256;
    for (size_t i = (size_t)blockIdx.x * 256 + threadIdx.x; i < 33554432ull; i += stride) {
        size_t e = i * 4;
        int ch = (int)((e >> 12) & 63) + (int)(e >> 23) * 64; // c + s*64
        float sc = a3[ch], sh = b3p[ch];
        f32x4 v = *(f32x4*)(out + e);
#pragma unroll
        for (int r = 0; r < 4; ++r) v[r] = fmaxf(fmaf(sc, v[r], sh), 0.f);
        *(f32x4*)(out + e) = v;
    }
}

extern "C" void kernel_launch(void* const* d_in, const int* in_sizes, int n_in,
                              void* d_out, int out_size, void* d_ws, size_t ws_size,
                              hipStream_t stream)
{
    const float* x   = (const float*)d_in[0];
    const float* w1  = (const float*)d_in[1];
    const float* b1  = (const float*)d_in[2];
    const float* g1  = (const float*)d_in[3];
    const float* be1 = (const float*)d_in[4];
    const float* w2  = (const float*)d_in[5];
    const float* b2  = (const float*)d_in[6];
    const float* g2  = (const float*)d_in[7];
    const float* be2 = (const float*)d_in[8];
    const float* w3  = (const float*)d_in[9];
    const float* b3  = (const float*)d_in[10];
    const float* g3  = (const float*)d_in[11];
    const float* be3 = (const float*)d_in[12];

    char* ws = (char*)d_ws;
    half_t* h1p = (half_t*)(ws + OFF_H1P);
    half_t* h2p = (half_t*)(ws + OFF_H2P);
    half_t* zr1 = (half_t*)(ws + OFF_ZR1);
    half_t* zr2 = (half_t*)(ws + OFF_ZR2);
    float*  wt1 = (float*)(ws + OFF_WT1);
    half_t* wt2 = (half_t*)(ws + OFF_WT2);
    half_t* wt3 = (half_t*)(ws + OFF_WT3);
    float*  sums = (float*)(ws + OFF_SUMS);
    float *s1v = sums, *s2v = sums + 1024, *s3v = sums + 3072;
    float*  prm = (float*)(ws + OFF_PRM);
    float *a1 = prm,        *b1p = prm + 512,  *t1 = prm + 1024;
    float *a2 = prm + 1536, *b2p = prm + 2560, *t2 = prm + 3584;
    float *a3 = prm + 4608, *b3p = prm + 5632, *t3 = prm + 6656;
    half_t* th = (half_t*)(ws + OFF_TH);
    half_t *th1 = th, *th2 = th + 512, *th3 = th + 1536;
    float* out = (float*)d_out;

    hipMemsetAsync(ws + OFF_SUMS, 0, 20480, stream);
    transform1_k<<<54, 256, 0, stream>>>(w1, wt1);
    dim3 grid1(16, 16, 32); // (tile, seed, sample)
    conv1_k<<<grid1, 256, 0, stream>>>(x, wt1, b1, h1p, s1v);
    bnparam_k<<<2, 256, 0, stream>>>(s1v, g1, be1, a1, b1p, t1, th1, 512);
    padfill_k<<<1041, 256, 0, stream>>>(h1p, zr1, t1, 32, 2, 135168L, 2112, 262144L, 266368L);
    wtrans2_k<<<1152, 256, 0, stream>>>(w2, a1, wt2);
    dim3 grid23(16, 16, 32); // (y-tile, seed, sample)
    conv2_k<<<grid23, 512, 0, stream>>>(h1p, zr1, wt2, b2, th1, h2p, s2v);
    bnparam_k<<<4, 256, 0, stream>>>(s2v, g2, be2, a2, b2p, t2, th2, 1024);
    padfill_k<<<2081, 256, 0, stream>>>(h2p, zr2, t2, 64, 3, 270336L, 4224, 524288L, 532736L);
    wtrans3_k<<<2304, 256, 0, stream>>>(w3, a2, wt3);
    conv3_k<<<grid23, 512, 0, stream>>>(h2p, zr2, wt3, b3, th2, out, s3v);
    bnparam_k<<<4, 256, 0, stream>>>(s3v, g3, be3, a3, b3p, t3, th3, 1024);
    final_k<<<4096, 256, 0, stream>>>(out, a3, b3p);
}